// Round 19
// baseline (24.934 us; speedup 1.0000x reference)
//
#include <hip/hip_runtime.h>

// CrossConvV2 — R18: occupancy re-test on the lean SoA structure.
// R5's 8192-wave test ran on the saturated 24B-stride pipe (null). Post-R16
// the pipe is lean; re-test: block = 512thr = 2 centers x half x nnH,
// 8192 waves, 4 iters/wave. LDS ~19.3KB -> 2 blocks/CU -> ~4 waves/SIMD
// resident (vs 2.4). All R14/R16/R17 numerics kept.

#define NPTS   1024
#define COEFF  10.0f
#define NEG    0.3f

typedef float  v2f __attribute__((ext_vector_type(2)));
typedef __fp16 h2  __attribute__((ext_vector_type(2)));

#define CA 4.24264068f   // 2*2.12132034
#define CY 3.91968890f   // 2*1.95984445
#define CZ 1.62358830f   // 2*0.81179415

// slot -> probe index (R9/R12-validated mapping)
constexpr int M0[14] = {0,5, 1,4, 2,3, 7,6, 8,12, 10,14, 24,25};
constexpr int M1[12] = {16,19, 17,18, 20,23, 21,22, 9,13, 11,15};

// ---- VOP3P packed f32 (all operands VGPR pairs; validated R14) ----
__device__ __forceinline__ v2f pk_fma(v2f a, v2f b, v2f c) {   // a*b+c
  v2f d;
  asm("v_pk_fma_f32 %0, %1, %2, %3" : "=v"(d) : "v"(a), "v"(b), "v"(c));
  return d;
}
__device__ __forceinline__ v2f pk_fma_n(v2f a, v2f b, v2f c) { // -a*b+c
  v2f d;
  asm("v_pk_fma_f32 %0, %1, %2, %3 neg_lo:[1,0,0] neg_hi:[1,0,0]"
      : "=v"(d) : "v"(a), "v"(b), "v"(c));
  return d;
}
__device__ __forceinline__ v2f pk_add(v2f a, v2f b) {          // a+b
  v2f d;
  asm("v_pk_add_f32 %0, %1, %2" : "=v"(d) : "v"(a), "v"(b));
  return d;
}
__device__ __forceinline__ v2f pk_sub(v2f a, v2f b) {          // a-b
  v2f d;
  asm("v_pk_add_f32 %0, %1, %2 neg_lo:[0,1] neg_hi:[0,1]"
      : "=v"(d) : "v"(a), "v"(b));
  return d;
}

// ---- wave64 f16x2 DPP reduce: 2 values per op chain ----
#define DPP_H2(x, ctrl, rm, bm, bc)                                          \
  x = x + __builtin_bit_cast(h2, __builtin_amdgcn_update_dpp(                \
      0, __builtin_bit_cast(int, x), ctrl, rm, bm, bc))

__device__ __forceinline__ h2 h2_wave_sum_to_lane63(h2 x) {
  DPP_H2(x, 0x111, 0xf, 0xf, true);   // row_shr:1
  DPP_H2(x, 0x112, 0xf, 0xf, true);   // row_shr:2
  DPP_H2(x, 0x114, 0xf, 0xe, false);  // row_shr:4
  DPP_H2(x, 0x118, 0xf, 0xc, false);  // row_shr:8
  DPP_H2(x, 0x142, 0xa, 0xf, false);  // row_bcast:15
  DPP_H2(x, 0x143, 0xc, 0xf, false);  // row_bcast:31
  return x;                            // lane 63 = full sum (x2)
}

// ---- rcp8: one v_rcp for 4 t-pairs (8 values); emits packed-f16 w ----
__device__ __forceinline__ void rcp8_cvt(const v2f* t, h2* wp) {
  const float p0 = t[0].x * t[0].y, p1 = t[1].x * t[1].y;
  const float p2 = t[2].x * t[2].y, p3 = t[3].x * t[3].y;
  const float q01 = p0 * p1, q23 = p2 * p3;
  const float r   = __builtin_amdgcn_rcpf(q01 * q23);
  const float r01 = q23 * r, r23 = q01 * r;
  const float i0 = p1 * r01, i1 = p0 * r01;
  const float i2 = p3 * r23, i3 = p2 * r23;
  wp[0] = __builtin_amdgcn_cvt_pkrtz(t[0].y * i0, t[0].x * i0);
  wp[1] = __builtin_amdgcn_cvt_pkrtz(t[1].y * i1, t[1].x * i1);
  wp[2] = __builtin_amdgcn_cvt_pkrtz(t[2].y * i2, t[2].x * i2);
  wp[3] = __builtin_amdgcn_cvt_pkrtz(t[3].y * i3, t[3].x * i3);
}
__device__ __forceinline__ void rcp4_cvt(const v2f* t, h2* wp) {
  const float p0 = t[0].x * t[0].y, p1 = t[1].x * t[1].y;
  const float r  = __builtin_amdgcn_rcpf(p0 * p1);
  const float i0 = p1 * r, i1 = p0 * r;
  wp[0] = __builtin_amdgcn_cvt_pkrtz(t[0].y * i0, t[0].x * i0);
  wp[1] = __builtin_amdgcn_cvt_pkrtz(t[1].y * i1, t[1].x * i1);
}

template <int HALF>
__device__ void run_main(const float* __restrict__ sxyz,   // 3*NPTS f32
                         const h2* __restrict__ sfeat,     // 3*(NPTS/2) h2
                         int nnH, int lane,
                         v2f cxp, v2f cyp, v2f czp, float* acc) {
  constexpr int NP = HALF ? 12 : 14;
  const v2f kCA = {CA, CA}, kCY = {CY, CY}, kCZ = {CZ, CZ};
  const v2f k6 = {6.f, 6.f}, k19 = {19.f, 19.f};

  v2f px[2], py[2], pz[2];
  h2  f0[2], f1[2], f2[2];

#define LOADIT(buf, it)                                                       \
  {                                                                           \
    const int nb = nnH * 512 + (it) * 128 + 2 * lane;                         \
    const int nh = nnH * 256 + (it) * 64 + lane;                              \
    px[buf] = *reinterpret_cast<const v2f*>(&sxyz[0 * NPTS + nb]);            \
    py[buf] = *reinterpret_cast<const v2f*>(&sxyz[1 * NPTS + nb]);            \
    pz[buf] = *reinterpret_cast<const v2f*>(&sxyz[2 * NPTS + nb]);            \
    f0[buf] = sfeat[0 * (NPTS / 2) + nh];                                     \
    f1[buf] = sfeat[1 * (NPTS / 2) + nh];                                     \
    f2[buf] = sfeat[2 * (NPTS / 2) + nh];                                     \
  }

  LOADIT(0, 0);
  #pragma unroll
  for (int it = 0; it < 4; ++it) {
    const int cur = it & 1, nxt = cur ^ 1;
    if (it < 3) LOADIT(nxt, it + 1);      // prefetch overlaps compute

    const v2f dx = pk_sub(px[cur], cxp);
    const v2f dy = pk_sub(py[cur], cyp);
    const v2f dz = pk_sub(pz[cur], czp);
    v2f base = pk_fma(dz, dz, k19);
    base = pk_fma(dy, dy, base);
    base = pk_fma(dx, dx, base);

    v2f t[NP];
    if constexpr (HALF == 0) {
      const v2f rx = pk_fma(kCA, dx, base);     // ring x=-2.1213
      const v2f sA = pk_fma  (kCZ, dz, rx);
      const v2f sB = pk_fma_n(kCZ, dz, rx);
      const v2f sC = pk_fma_n(kCY, dz, rx);
      const v2f sD = pk_fma  (kCY, dz, rx);
      t[0]  = pk_fma_n(kCY, dy, sA);  t[1]  = pk_fma(kCY, dy, sA);  // p0,p5
      t[2]  = pk_fma_n(kCY, dy, sB);  t[3]  = pk_fma(kCY, dy, sB);  // p1,p4
      t[4]  = pk_fma_n(kCZ, dy, sC);  t[5]  = pk_fma(kCZ, dy, sC);  // p2,p3
      t[6]  = pk_fma_n(kCZ, dy, sD);  t[7]  = pk_fma(kCZ, dy, sD);  // p7,p6
      t[8]  = pk_fma_n(k6, dy, base); t[9]  = pk_fma(k6, dy, base); // p8,p12
      t[10] = pk_fma_n(k6, dz, base); t[11] = pk_fma(k6, dz, base); // p10,p14
      t[12] = pk_fma  (k6, dx, base); t[13] = pk_fma_n(k6, dx, base);// p24,p25
    } else {
      const v2f rx = pk_fma_n(kCA, dx, base);   // ring x=+2.1213
      const v2f sA = pk_fma_n(kCZ, dz, rx);
      const v2f sB = pk_fma_n(kCY, dz, rx);
      const v2f sC = pk_fma  (kCZ, dz, rx);
      const v2f sD = pk_fma  (kCY, dz, rx);
      const v2f u = pk_add(dy, dz), v = pk_sub(dy, dz);
      t[0]  = pk_fma_n(kCY, dy, sA);  t[1]  = pk_fma(kCY, dy, sA);  // p16,p19
      t[2]  = pk_fma_n(kCZ, dy, sB);  t[3]  = pk_fma(kCZ, dy, sB);  // p17,p18
      t[4]  = pk_fma  (kCY, dy, sC);  t[5]  = pk_fma_n(kCY, dy, sC);// p20,p23
      t[6]  = pk_fma  (kCZ, dy, sD);  t[7]  = pk_fma_n(kCZ, dy, sD);// p21,p22
      t[8]  = pk_fma_n(kCA, u, base); t[9]  = pk_fma(kCA, u, base); // p9,p13
      t[10] = pk_fma  (kCA, v, base); t[11] = pk_fma_n(kCA, v, base);// p11,p15
    }

    h2 wp[NP];
    rcp8_cvt(t + 0, wp + 0);
    rcp8_cvt(t + 4, wp + 4);
    rcp8_cvt(t + 8, wp + 8);
    if constexpr (NP == 14) rcp4_cvt(t + 12, wp + 12);

    #pragma unroll
    for (int j = 0; j < NP; ++j) {
      acc[j * 3 + 0] = __builtin_amdgcn_fdot2(wp[j], f0[cur], acc[j * 3 + 0], false);
      acc[j * 3 + 1] = __builtin_amdgcn_fdot2(wp[j], f1[cur], acc[j * 3 + 1], false);
      acc[j * 3 + 2] = __builtin_amdgcn_fdot2(wp[j], f2[cur], acc[j * 3 + 2], false);
    }
  }
#undef LOADIT
}

// packed f16x2 reduce of NP*3 accs; lane 63 unpacks into f32 sx slot
template <int HALF>
__device__ __forceinline__ void reduce_store(float* acc, int lane, float* sx) {
  constexpr int NP = HALF ? 12 : 14;
  constexpr int NH = NP * 3 / 2;            // 21 or 18 h2 regs
  h2 red[NH];
  #pragma unroll
  for (int p = 0; p < NH; ++p)
    red[p] = __builtin_amdgcn_cvt_pkrtz(acc[2 * p], acc[2 * p + 1]);
  #pragma unroll
  for (int p = 0; p < NH; ++p)
    red[p] = h2_wave_sum_to_lane63(red[p]);
  if (lane == 63) {
    #pragma unroll
    for (int p = 0; p < NH; ++p) {
      const int a0 = 2 * p, a1 = 2 * p + 1;
      const int m0 = (HALF ? M1[a0 / 3] : M0[a0 / 3]);
      const int m1 = (HALF ? M1[a1 / 3] : M0[a1 / 3]);
      sx[m0 * 3 + a0 % 3] = (float)red[p].x;
      sx[m1 * 3 + a1 % 3] = (float)red[p].y;
    }
  }
}

__global__ __launch_bounds__(512, 4) void crossconv_kernel(
    const float* __restrict__ points,  // (2,1024,6)
    const float* __restrict__ W,       // (5,78,6)
    const float* __restrict__ bias,    // (5,6) flat 30
    float* __restrict__ out)           // (2,1024,33)
{
    __shared__ __align__(16) float sxyz[3 * NPTS];       // 12 KB coords f32
    __shared__ __align__(16) h2    sfeat[3 * NPTS / 2];  // 6 KB feats f16
    __shared__ __align__(16) float sx[2][2][80];         // [center][nnH][val]

    const int tid    = threadIdx.x;
    const int lane   = tid & 63;
    const int w      = tid >> 6;          // wave in block: 0..7
    const int cLocal = w >> 2;            // center within block: 0,1
    const int half   = (w >> 1) & 1;      // probe half: 0,1
    const int nnH    = w & 1;             // neighbor half: 0,1
    const int G      = blockIdx.x * 2 + cLocal;   // global center 0..2047

    const float* batch = points + (G >> 10) * (NPTS * 6);

    // ---- one-time SoA transpose: thread t handles rows 2t, 2t+1 ----
    {
      const float4* src4 = reinterpret_cast<const float4*>(batch) + 3 * tid;
      const float4 q0 = src4[0], q1 = src4[1], q2 = src4[2];
      const int r = 2 * tid;
      sxyz[0*NPTS + r+0] = q0.x; sxyz[1*NPTS + r+0] = q0.y; sxyz[2*NPTS + r+0] = q0.z;
      sxyz[0*NPTS + r+1] = q1.z; sxyz[1*NPTS + r+1] = q1.w; sxyz[2*NPTS + r+1] = q2.x;
      sfeat[0*(NPTS/2) + tid] = __builtin_amdgcn_cvt_pkrtz(q0.w, q2.y);  // f0
      sfeat[1*(NPTS/2) + tid] = __builtin_amdgcn_cvt_pkrtz(q1.x, q2.z);  // f1
      sfeat[2*(NPTS/2) + tid] = __builtin_amdgcn_cvt_pkrtz(q1.y, q2.w);  // f2
    }
    __syncthreads();

    const int   ci = ((blockIdx.x & 511) << 1) | cLocal;  // center row in batch
    const float cx = sxyz[0*NPTS + ci], cy = sxyz[1*NPTS + ci], cz = sxyz[2*NPTS + ci];
    const v2f cxp = {cx, cx}, cyp = {cy, cy}, czp = {cz, cz};

    float acc[42];
    #pragma unroll
    for (int j = 0; j < 42; ++j) acc[j] = 0.f;

    if (half == 0) run_main<0>(sxyz, sfeat, nnH, lane, cxp, cyp, czp, acc);
    else           run_main<1>(sxyz, sfeat, nnH, lane, cxp, cyp, czp, acc);

    if (half == 0) reduce_store<0>(acc, lane, sx[cLocal][nnH]);
    else           reduce_store<1>(acc, lane, sx[cLocal][nnH]);
    __syncthreads();

    // tail: waves 0 (c0) and 4 (c1) do the 78->30 matmul + coords
    if ((w & 3) == 0) {
      const float scale = COEFF / (float)NPTS;
      float* orow = out + G * 33;
      if (lane < 30) {
        const int k = lane / 6, o = lane % 6;
        const float* Wk = W + k * (78 * 6) + o;  // W[k, t, o], stride 6 over t
        float h0 = 0.f, h1 = 0.f, h2_ = 0.f, h3 = 0.f;
        const float4* s0 = reinterpret_cast<const float4*>(sx[cLocal][0]);
        const float4* s1 = reinterpret_cast<const float4*>(sx[cLocal][1]);
        #pragma unroll
        for (int t4 = 0; t4 < 19; ++t4) {
          const float4 va = s0[t4], vb = s1[t4];
          h0  = fmaf(va.x + vb.x, Wk[(t4 * 4 + 0) * 6], h0);
          h1  = fmaf(va.y + vb.y, Wk[(t4 * 4 + 1) * 6], h1);
          h2_ = fmaf(va.z + vb.z, Wk[(t4 * 4 + 2) * 6], h2_);
          h3  = fmaf(va.w + vb.w, Wk[(t4 * 4 + 3) * 6], h3);
        }
        h0 = fmaf(sx[cLocal][0][76] + sx[cLocal][1][76], Wk[76 * 6], h0);
        h1 = fmaf(sx[cLocal][0][77] + sx[cLocal][1][77], Wk[77 * 6], h1);
        const float dot = (h0 + h2_) + (h1 + h3);
        float h = fmaf(dot, scale, bias[lane]);
        h = (h > 0.f) ? h : NEG * h;
        orow[3 + lane] = h;
      } else if (lane < 33) {
        orow[lane - 30] = (lane == 30) ? cx : ((lane == 31) ? cy : cz);
      }
    }
}

extern "C" void kernel_launch(void* const* d_in, const int* in_sizes, int n_in,
                              void* d_out, int out_size, void* d_ws, size_t ws_size,
                              hipStream_t stream) {
    const float* points = (const float*)d_in[0];  // 2*1024*6
    const float* W      = (const float*)d_in[1];  // 5*78*6
    const float* bias   = (const float*)d_in[2];  // 30
    float* out          = (float*)d_out;          // 2*1024*33
    // 1024 blocks x 8 waves = 2048 centers x half x nnH = 8192 waves
    crossconv_kernel<<<1024, 512, 0, stream>>>(points, W, bias, out);
}

// Round 20
// 23.171 us; speedup vs baseline: 1.0761x; 1.0761x over previous
//
#include <hip/hip_runtime.h>

// CrossConvV2 — R19: final combined push on R17 (best: 21.37us).
//  1) 4 centers/block (512thr, 8 waves = 4c x probe-half, NO nn-split):
//     halves block count -> halves redundant transpose + ramp (fixed term).
//  2) rcp4 instead of rcp8: same op count, dep chain 7->5 levels; extra
//     rcps go to the idle trans pipe (marginal-term stall).
// All other numerics byte-identical to R17 (pk-f32 asm, fdot2, f16x2 reduce).

#define NPTS   1024
#define COEFF  10.0f
#define NEG    0.3f

typedef float  v2f __attribute__((ext_vector_type(2)));
typedef __fp16 h2  __attribute__((ext_vector_type(2)));

#define CA 4.24264068f   // 2*2.12132034
#define CY 3.91968890f   // 2*1.95984445
#define CZ 1.62358830f   // 2*0.81179415

// slot -> probe index (R9/R12-validated mapping)
constexpr int M0[14] = {0,5, 1,4, 2,3, 7,6, 8,12, 10,14, 24,25};
constexpr int M1[12] = {16,19, 17,18, 20,23, 21,22, 9,13, 11,15};

// ---- VOP3P packed f32 (all operands VGPR pairs; validated R14) ----
__device__ __forceinline__ v2f pk_fma(v2f a, v2f b, v2f c) {   // a*b+c
  v2f d;
  asm("v_pk_fma_f32 %0, %1, %2, %3" : "=v"(d) : "v"(a), "v"(b), "v"(c));
  return d;
}
__device__ __forceinline__ v2f pk_fma_n(v2f a, v2f b, v2f c) { // -a*b+c
  v2f d;
  asm("v_pk_fma_f32 %0, %1, %2, %3 neg_lo:[1,0,0] neg_hi:[1,0,0]"
      : "=v"(d) : "v"(a), "v"(b), "v"(c));
  return d;
}
__device__ __forceinline__ v2f pk_add(v2f a, v2f b) {          // a+b
  v2f d;
  asm("v_pk_add_f32 %0, %1, %2" : "=v"(d) : "v"(a), "v"(b));
  return d;
}
__device__ __forceinline__ v2f pk_sub(v2f a, v2f b) {          // a-b
  v2f d;
  asm("v_pk_add_f32 %0, %1, %2 neg_lo:[0,1] neg_hi:[0,1]"
      : "=v"(d) : "v"(a), "v"(b));
  return d;
}

// ---- wave64 f16x2 DPP reduce: 2 values per op chain ----
#define DPP_H2(x, ctrl, rm, bm, bc)                                          \
  x = x + __builtin_bit_cast(h2, __builtin_amdgcn_update_dpp(                \
      0, __builtin_bit_cast(int, x), ctrl, rm, bm, bc))

__device__ __forceinline__ h2 h2_wave_sum_to_lane63(h2 x) {
  DPP_H2(x, 0x111, 0xf, 0xf, true);   // row_shr:1
  DPP_H2(x, 0x112, 0xf, 0xf, true);   // row_shr:2
  DPP_H2(x, 0x114, 0xf, 0xe, false);  // row_shr:4
  DPP_H2(x, 0x118, 0xf, 0xc, false);  // row_shr:8
  DPP_H2(x, 0x142, 0xa, 0xf, false);  // row_bcast:15
  DPP_H2(x, 0x143, 0xc, 0xf, false);  // row_bcast:31
  return x;                            // lane 63 = full sum (x2)
}

// ---- rcp4: one v_rcp per 2 t-pairs (4 values), shallow 5-level chain ----
__device__ __forceinline__ void rcp4_cvt(const v2f* t, h2* wp) {
  const float p0 = t[0].x * t[0].y, p1 = t[1].x * t[1].y;
  const float r  = __builtin_amdgcn_rcpf(p0 * p1);
  const float i0 = p1 * r, i1 = p0 * r;
  wp[0] = __builtin_amdgcn_cvt_pkrtz(t[0].y * i0, t[0].x * i0);
  wp[1] = __builtin_amdgcn_cvt_pkrtz(t[1].y * i1, t[1].x * i1);
}

template <int HALF>
__device__ void run_main(const float* __restrict__ sxyz,   // 3*NPTS f32
                         const h2* __restrict__ sfeat,     // 3*(NPTS/2) h2
                         int lane, v2f cxp, v2f cyp, v2f czp, float* acc) {
  constexpr int NP = HALF ? 12 : 14;
  const v2f kCA = {CA, CA}, kCY = {CY, CY}, kCZ = {CZ, CZ};
  const v2f k6 = {6.f, 6.f}, k19 = {19.f, 19.f};

  v2f px[2], py[2], pz[2];
  h2  f0[2], f1[2], f2[2];

#define LOADIT(buf, it)                                                       \
  {                                                                           \
    const int nb = (it) * 128 + 2 * lane;                                     \
    const int nh = (it) * 64 + lane;                                          \
    px[buf] = *reinterpret_cast<const v2f*>(&sxyz[0 * NPTS + nb]);            \
    py[buf] = *reinterpret_cast<const v2f*>(&sxyz[1 * NPTS + nb]);            \
    pz[buf] = *reinterpret_cast<const v2f*>(&sxyz[2 * NPTS + nb]);            \
    f0[buf] = sfeat[0 * (NPTS / 2) + nh];                                     \
    f1[buf] = sfeat[1 * (NPTS / 2) + nh];                                     \
    f2[buf] = sfeat[2 * (NPTS / 2) + nh];                                     \
  }

  LOADIT(0, 0);
  #pragma unroll
  for (int it = 0; it < 8; ++it) {
    const int cur = it & 1, nxt = cur ^ 1;
    if (it < 7) LOADIT(nxt, it + 1);      // prefetch overlaps compute

    const v2f dx = pk_sub(px[cur], cxp);
    const v2f dy = pk_sub(py[cur], cyp);
    const v2f dz = pk_sub(pz[cur], czp);
    v2f base = pk_fma(dz, dz, k19);
    base = pk_fma(dy, dy, base);
    base = pk_fma(dx, dx, base);

    v2f t[NP];
    if constexpr (HALF == 0) {
      const v2f rx = pk_fma(kCA, dx, base);     // ring x=-2.1213
      const v2f sA = pk_fma  (kCZ, dz, rx);
      const v2f sB = pk_fma_n(kCZ, dz, rx);
      const v2f sC = pk_fma_n(kCY, dz, rx);
      const v2f sD = pk_fma  (kCY, dz, rx);
      t[0]  = pk_fma_n(kCY, dy, sA);  t[1]  = pk_fma(kCY, dy, sA);  // p0,p5
      t[2]  = pk_fma_n(kCY, dy, sB);  t[3]  = pk_fma(kCY, dy, sB);  // p1,p4
      t[4]  = pk_fma_n(kCZ, dy, sC);  t[5]  = pk_fma(kCZ, dy, sC);  // p2,p3
      t[6]  = pk_fma_n(kCZ, dy, sD);  t[7]  = pk_fma(kCZ, dy, sD);  // p7,p6
      t[8]  = pk_fma_n(k6, dy, base); t[9]  = pk_fma(k6, dy, base); // p8,p12
      t[10] = pk_fma_n(k6, dz, base); t[11] = pk_fma(k6, dz, base); // p10,p14
      t[12] = pk_fma  (k6, dx, base); t[13] = pk_fma_n(k6, dx, base);// p24,p25
    } else {
      const v2f rx = pk_fma_n(kCA, dx, base);   // ring x=+2.1213
      const v2f sA = pk_fma_n(kCZ, dz, rx);
      const v2f sB = pk_fma_n(kCY, dz, rx);
      const v2f sC = pk_fma  (kCZ, dz, rx);
      const v2f sD = pk_fma  (kCY, dz, rx);
      const v2f u = pk_add(dy, dz), v = pk_sub(dy, dz);
      t[0]  = pk_fma_n(kCY, dy, sA);  t[1]  = pk_fma(kCY, dy, sA);  // p16,p19
      t[2]  = pk_fma_n(kCZ, dy, sB);  t[3]  = pk_fma(kCZ, dy, sB);  // p17,p18
      t[4]  = pk_fma  (kCY, dy, sC);  t[5]  = pk_fma_n(kCY, dy, sC);// p20,p23
      t[6]  = pk_fma  (kCZ, dy, sD);  t[7]  = pk_fma_n(kCZ, dy, sD);// p21,p22
      t[8]  = pk_fma_n(kCA, u, base); t[9]  = pk_fma(kCA, u, base); // p9,p13
      t[10] = pk_fma  (kCA, v, base); t[11] = pk_fma_n(kCA, v, base);// p11,p15
    }

    h2 wp[NP];
    rcp4_cvt(t + 0,  wp + 0);
    rcp4_cvt(t + 2,  wp + 2);
    rcp4_cvt(t + 4,  wp + 4);
    rcp4_cvt(t + 6,  wp + 6);
    rcp4_cvt(t + 8,  wp + 8);
    rcp4_cvt(t + 10, wp + 10);
    if constexpr (NP == 14) rcp4_cvt(t + 12, wp + 12);

    #pragma unroll
    for (int j = 0; j < NP; ++j) {
      acc[j * 3 + 0] = __builtin_amdgcn_fdot2(wp[j], f0[cur], acc[j * 3 + 0], false);
      acc[j * 3 + 1] = __builtin_amdgcn_fdot2(wp[j], f1[cur], acc[j * 3 + 1], false);
      acc[j * 3 + 2] = __builtin_amdgcn_fdot2(wp[j], f2[cur], acc[j * 3 + 2], false);
    }
  }
#undef LOADIT
}

// packed f16x2 reduce of NP*3 accs; lane 63 unpacks into f32 sx slot
template <int HALF>
__device__ __forceinline__ void reduce_store(float* acc, int lane, float* sx) {
  constexpr int NP = HALF ? 12 : 14;
  constexpr int NH = NP * 3 / 2;            // 21 or 18 h2 regs
  h2 red[NH];
  #pragma unroll
  for (int p = 0; p < NH; ++p)
    red[p] = __builtin_amdgcn_cvt_pkrtz(acc[2 * p], acc[2 * p + 1]);
  #pragma unroll
  for (int p = 0; p < NH; ++p)
    red[p] = h2_wave_sum_to_lane63(red[p]);
  if (lane == 63) {
    #pragma unroll
    for (int p = 0; p < NH; ++p) {
      const int a0 = 2 * p, a1 = 2 * p + 1;
      const int m0 = (HALF ? M1[a0 / 3] : M0[a0 / 3]);
      const int m1 = (HALF ? M1[a1 / 3] : M0[a1 / 3]);
      sx[m0 * 3 + a0 % 3] = (float)red[p].x;
      sx[m1 * 3 + a1 % 3] = (float)red[p].y;
    }
  }
}

__global__ __launch_bounds__(512, 4) void crossconv_kernel(
    const float* __restrict__ points,  // (2,1024,6)
    const float* __restrict__ W,       // (5,78,6)
    const float* __restrict__ bias,    // (5,6) flat 30
    float* __restrict__ out)           // (2,1024,33)
{
    __shared__ __align__(16) float sxyz[3 * NPTS];       // 12 KB coords f32
    __shared__ __align__(16) h2    sfeat[3 * NPTS / 2];  // 6 KB feats f16
    __shared__ __align__(16) float sx[4][80];            // 4 centers

    const int tid    = threadIdx.x;
    const int lane   = tid & 63;
    const int w      = tid >> 6;          // wave in block: 0..7
    const int cLocal = w >> 1;            // center within block: 0..3
    const int half   = w & 1;             // probe half: 0,1
    const int G      = blockIdx.x * 4 + cLocal;   // global center 0..2047

    const float* batch = points + (G >> 10) * (NPTS * 6);

    // ---- one-time SoA transpose: thread t handles rows 2t, 2t+1 ----
    {
      const float4* src4 = reinterpret_cast<const float4*>(batch) + 3 * tid;
      const float4 q0 = src4[0], q1 = src4[1], q2 = src4[2];
      const int r = 2 * tid;
      sxyz[0*NPTS + r+0] = q0.x; sxyz[1*NPTS + r+0] = q0.y; sxyz[2*NPTS + r+0] = q0.z;
      sxyz[0*NPTS + r+1] = q1.z; sxyz[1*NPTS + r+1] = q1.w; sxyz[2*NPTS + r+1] = q2.x;
      sfeat[0*(NPTS/2) + tid] = __builtin_amdgcn_cvt_pkrtz(q0.w, q2.y);  // f0
      sfeat[1*(NPTS/2) + tid] = __builtin_amdgcn_cvt_pkrtz(q1.x, q2.z);  // f1
      sfeat[2*(NPTS/2) + tid] = __builtin_amdgcn_cvt_pkrtz(q1.y, q2.w);  // f2
    }
    __syncthreads();

    const int   ci = ((blockIdx.x & 255) << 2) | cLocal;  // center row in batch
    const float cx = sxyz[0*NPTS + ci], cy = sxyz[1*NPTS + ci], cz = sxyz[2*NPTS + ci];
    const v2f cxp = {cx, cx}, cyp = {cy, cy}, czp = {cz, cz};

    float acc[42];
    #pragma unroll
    for (int j = 0; j < 42; ++j) acc[j] = 0.f;

    if (half == 0) run_main<0>(sxyz, sfeat, lane, cxp, cyp, czp, acc);
    else           run_main<1>(sxyz, sfeat, lane, cxp, cyp, czp, acc);

    if (half == 0) reduce_store<0>(acc, lane, sx[cLocal]);
    else           reduce_store<1>(acc, lane, sx[cLocal]);
    __syncthreads();

    // tail: even waves do the 78->30 matmul + coords for their center
    if (half == 0) {
      const float scale = COEFF / (float)NPTS;
      float* orow = out + G * 33;
      if (lane < 30) {
        const int k = lane / 6, o = lane % 6;
        const float* Wk = W + k * (78 * 6) + o;  // W[k, t, o], stride 6 over t
        float h0 = 0.f, h1 = 0.f, h2_ = 0.f, h3 = 0.f;
        const float4* sxv = reinterpret_cast<const float4*>(sx[cLocal]);
        #pragma unroll
        for (int t4 = 0; t4 < 19; ++t4) {
          const float4 v = sxv[t4];
          h0  = fmaf(v.x, Wk[(t4 * 4 + 0) * 6], h0);
          h1  = fmaf(v.y, Wk[(t4 * 4 + 1) * 6], h1);
          h2_ = fmaf(v.z, Wk[(t4 * 4 + 2) * 6], h2_);
          h3  = fmaf(v.w, Wk[(t4 * 4 + 3) * 6], h3);
        }
        const float2 vt = *reinterpret_cast<const float2*>(&sx[cLocal][76]);
        h0 = fmaf(vt.x, Wk[76 * 6], h0);
        h1 = fmaf(vt.y, Wk[77 * 6], h1);
        const float dot = (h0 + h2_) + (h1 + h3);
        float h = fmaf(dot, scale, bias[lane]);
        h = (h > 0.f) ? h : NEG * h;
        orow[3 + lane] = h;
      } else if (lane < 33) {
        orow[lane - 30] = (lane == 30) ? cx : ((lane == 31) ? cy : cz);
      }
    }
}

extern "C" void kernel_launch(void* const* d_in, const int* in_sizes, int n_in,
                              void* d_out, int out_size, void* d_ws, size_t ws_size,
                              hipStream_t stream) {
    const float* points = (const float*)d_in[0];  // 2*1024*6
    const float* W      = (const float*)d_in[1];  // 5*78*6
    const float* bias   = (const float*)d_in[2];  // 30
    float* out          = (float*)d_out;          // 2*1024*33
    // 512 blocks x 8 waves = 2048 centers x 2 probe-halves = 4096 waves
    crossconv_kernel<<<512, 512, 0, stream>>>(points, W, bias, out);
}

// Round 21
// 21.172 us; speedup vs baseline: 1.1777x; 1.0944x over previous
//
#include <hip/hip_runtime.h>

// CrossConvV2 — R20: revert to R17, the measured optimum (21.37us).
// R19's tweaks (4c/512thr block, rcp4) regressed to 23.2; R18 (occupancy)
// 24.9; R15 (load-share) 25.2. R17 = SoA-f32-coords + f16-feats in LDS,
// 2-deep reg pipeline, pk-f32 asm t-gen, rcp8 batch, fdot2 acc, f16x2
// DPP reduce, 1024 blocks x 4 waves (2 centers x probe-half).

#define NPTS   1024
#define COEFF  10.0f
#define NEG    0.3f

typedef float  v2f __attribute__((ext_vector_type(2)));
typedef __fp16 h2  __attribute__((ext_vector_type(2)));

#define CA 4.24264068f   // 2*2.12132034
#define CY 3.91968890f   // 2*1.95984445
#define CZ 1.62358830f   // 2*0.81179415

// slot -> probe index (R9/R12-validated mapping)
constexpr int M0[14] = {0,5, 1,4, 2,3, 7,6, 8,12, 10,14, 24,25};
constexpr int M1[12] = {16,19, 17,18, 20,23, 21,22, 9,13, 11,15};

// ---- VOP3P packed f32 (all operands VGPR pairs; validated R14) ----
__device__ __forceinline__ v2f pk_fma(v2f a, v2f b, v2f c) {   // a*b+c
  v2f d;
  asm("v_pk_fma_f32 %0, %1, %2, %3" : "=v"(d) : "v"(a), "v"(b), "v"(c));
  return d;
}
__device__ __forceinline__ v2f pk_fma_n(v2f a, v2f b, v2f c) { // -a*b+c
  v2f d;
  asm("v_pk_fma_f32 %0, %1, %2, %3 neg_lo:[1,0,0] neg_hi:[1,0,0]"
      : "=v"(d) : "v"(a), "v"(b), "v"(c));
  return d;
}
__device__ __forceinline__ v2f pk_add(v2f a, v2f b) {          // a+b
  v2f d;
  asm("v_pk_add_f32 %0, %1, %2" : "=v"(d) : "v"(a), "v"(b));
  return d;
}
__device__ __forceinline__ v2f pk_sub(v2f a, v2f b) {          // a-b
  v2f d;
  asm("v_pk_add_f32 %0, %1, %2 neg_lo:[0,1] neg_hi:[0,1]"
      : "=v"(d) : "v"(a), "v"(b));
  return d;
}

// ---- wave64 f16x2 DPP reduce: 2 values per op chain ----
#define DPP_H2(x, ctrl, rm, bm, bc)                                          \
  x = x + __builtin_bit_cast(h2, __builtin_amdgcn_update_dpp(                \
      0, __builtin_bit_cast(int, x), ctrl, rm, bm, bc))

__device__ __forceinline__ h2 h2_wave_sum_to_lane63(h2 x) {
  DPP_H2(x, 0x111, 0xf, 0xf, true);   // row_shr:1
  DPP_H2(x, 0x112, 0xf, 0xf, true);   // row_shr:2
  DPP_H2(x, 0x114, 0xf, 0xe, false);  // row_shr:4
  DPP_H2(x, 0x118, 0xf, 0xc, false);  // row_shr:8
  DPP_H2(x, 0x142, 0xa, 0xf, false);  // row_bcast:15
  DPP_H2(x, 0x143, 0xc, 0xf, false);  // row_bcast:31
  return x;                            // lane 63 = full sum (x2)
}

// ---- rcp8: one v_rcp for 4 t-pairs (8 values); emits packed-f16 w ----
__device__ __forceinline__ void rcp8_cvt(const v2f* t, h2* wp) {
  const float p0 = t[0].x * t[0].y, p1 = t[1].x * t[1].y;
  const float p2 = t[2].x * t[2].y, p3 = t[3].x * t[3].y;
  const float q01 = p0 * p1, q23 = p2 * p3;
  const float r   = __builtin_amdgcn_rcpf(q01 * q23);
  const float r01 = q23 * r, r23 = q01 * r;
  const float i0 = p1 * r01, i1 = p0 * r01;
  const float i2 = p3 * r23, i3 = p2 * r23;
  wp[0] = __builtin_amdgcn_cvt_pkrtz(t[0].y * i0, t[0].x * i0);
  wp[1] = __builtin_amdgcn_cvt_pkrtz(t[1].y * i1, t[1].x * i1);
  wp[2] = __builtin_amdgcn_cvt_pkrtz(t[2].y * i2, t[2].x * i2);
  wp[3] = __builtin_amdgcn_cvt_pkrtz(t[3].y * i3, t[3].x * i3);
}
__device__ __forceinline__ void rcp4_cvt(const v2f* t, h2* wp) {
  const float p0 = t[0].x * t[0].y, p1 = t[1].x * t[1].y;
  const float r  = __builtin_amdgcn_rcpf(p0 * p1);
  const float i0 = p1 * r, i1 = p0 * r;
  wp[0] = __builtin_amdgcn_cvt_pkrtz(t[0].y * i0, t[0].x * i0);
  wp[1] = __builtin_amdgcn_cvt_pkrtz(t[1].y * i1, t[1].x * i1);
}

template <int HALF>
__device__ void run_main(const float* __restrict__ sxyz,   // 3*NPTS f32
                         const h2* __restrict__ sfeat,     // 3*(NPTS/2) h2
                         int lane, v2f cxp, v2f cyp, v2f czp, float* acc) {
  constexpr int NP = HALF ? 12 : 14;
  const v2f kCA = {CA, CA}, kCY = {CY, CY}, kCZ = {CZ, CZ};
  const v2f k6 = {6.f, 6.f}, k19 = {19.f, 19.f};

  // register double-buffer for the 2-deep pipeline
  v2f px[2], py[2], pz[2];
  h2  f0[2], f1[2], f2[2];

#define LOADIT(buf, it)                                                       \
  {                                                                           \
    const int nb = (it) * 128 + 2 * lane;                                     \
    const int nh = (it) * 64 + lane;                                          \
    px[buf] = *reinterpret_cast<const v2f*>(&sxyz[0 * NPTS + nb]);            \
    py[buf] = *reinterpret_cast<const v2f*>(&sxyz[1 * NPTS + nb]);            \
    pz[buf] = *reinterpret_cast<const v2f*>(&sxyz[2 * NPTS + nb]);            \
    f0[buf] = sfeat[0 * (NPTS / 2) + nh];                                     \
    f1[buf] = sfeat[1 * (NPTS / 2) + nh];                                     \
    f2[buf] = sfeat[2 * (NPTS / 2) + nh];                                     \
  }

  LOADIT(0, 0);
  #pragma unroll
  for (int it = 0; it < 8; ++it) {
    const int cur = it & 1, nxt = cur ^ 1;
    if (it < 7) LOADIT(nxt, it + 1);      // prefetch overlaps compute below

    const v2f dx = pk_sub(px[cur], cxp);
    const v2f dy = pk_sub(py[cur], cyp);
    const v2f dz = pk_sub(pz[cur], czp);
    v2f base = pk_fma(dz, dz, k19);
    base = pk_fma(dy, dy, base);
    base = pk_fma(dx, dx, base);

    v2f t[NP];
    if constexpr (HALF == 0) {
      const v2f rx = pk_fma(kCA, dx, base);     // ring x=-2.1213
      const v2f sA = pk_fma  (kCZ, dz, rx);
      const v2f sB = pk_fma_n(kCZ, dz, rx);
      const v2f sC = pk_fma_n(kCY, dz, rx);
      const v2f sD = pk_fma  (kCY, dz, rx);
      t[0]  = pk_fma_n(kCY, dy, sA);  t[1]  = pk_fma(kCY, dy, sA);  // p0,p5
      t[2]  = pk_fma_n(kCY, dy, sB);  t[3]  = pk_fma(kCY, dy, sB);  // p1,p4
      t[4]  = pk_fma_n(kCZ, dy, sC);  t[5]  = pk_fma(kCZ, dy, sC);  // p2,p3
      t[6]  = pk_fma_n(kCZ, dy, sD);  t[7]  = pk_fma(kCZ, dy, sD);  // p7,p6
      t[8]  = pk_fma_n(k6, dy, base); t[9]  = pk_fma(k6, dy, base); // p8,p12
      t[10] = pk_fma_n(k6, dz, base); t[11] = pk_fma(k6, dz, base); // p10,p14
      t[12] = pk_fma  (k6, dx, base); t[13] = pk_fma_n(k6, dx, base);// p24,p25
    } else {
      const v2f rx = pk_fma_n(kCA, dx, base);   // ring x=+2.1213
      const v2f sA = pk_fma_n(kCZ, dz, rx);
      const v2f sB = pk_fma_n(kCY, dz, rx);
      const v2f sC = pk_fma  (kCZ, dz, rx);
      const v2f sD = pk_fma  (kCY, dz, rx);
      const v2f u = pk_add(dy, dz), v = pk_sub(dy, dz);
      t[0]  = pk_fma_n(kCY, dy, sA);  t[1]  = pk_fma(kCY, dy, sA);  // p16,p19
      t[2]  = pk_fma_n(kCZ, dy, sB);  t[3]  = pk_fma(kCZ, dy, sB);  // p17,p18
      t[4]  = pk_fma  (kCY, dy, sC);  t[5]  = pk_fma_n(kCY, dy, sC);// p20,p23
      t[6]  = pk_fma  (kCZ, dy, sD);  t[7]  = pk_fma_n(kCZ, dy, sD);// p21,p22
      t[8]  = pk_fma_n(kCA, u, base); t[9]  = pk_fma(kCA, u, base); // p9,p13
      t[10] = pk_fma  (kCA, v, base); t[11] = pk_fma_n(kCA, v, base);// p11,p15
    }

    h2 wp[NP];
    rcp8_cvt(t + 0, wp + 0);
    rcp8_cvt(t + 4, wp + 4);
    rcp8_cvt(t + 8, wp + 8);
    if constexpr (NP == 14) rcp4_cvt(t + 12, wp + 12);

    #pragma unroll
    for (int j = 0; j < NP; ++j) {
      acc[j * 3 + 0] = __builtin_amdgcn_fdot2(wp[j], f0[cur], acc[j * 3 + 0], false);
      acc[j * 3 + 1] = __builtin_amdgcn_fdot2(wp[j], f1[cur], acc[j * 3 + 1], false);
      acc[j * 3 + 2] = __builtin_amdgcn_fdot2(wp[j], f2[cur], acc[j * 3 + 2], false);
    }
  }
#undef LOADIT
}

// packed f16x2 reduce of NP*3 accs; lane 63 unpacks into f32 sx slot
template <int HALF>
__device__ __forceinline__ void reduce_store(float* acc, int lane, float* sx) {
  constexpr int NP = HALF ? 12 : 14;
  constexpr int NH = NP * 3 / 2;            // 21 or 18 h2 regs
  h2 red[NH];
  #pragma unroll
  for (int p = 0; p < NH; ++p)
    red[p] = __builtin_amdgcn_cvt_pkrtz(acc[2 * p], acc[2 * p + 1]);
  #pragma unroll
  for (int p = 0; p < NH; ++p)
    red[p] = h2_wave_sum_to_lane63(red[p]);
  if (lane == 63) {
    #pragma unroll
    for (int p = 0; p < NH; ++p) {
      const int a0 = 2 * p, a1 = 2 * p + 1;
      const int m0 = (HALF ? M1[a0 / 3] : M0[a0 / 3]);
      const int m1 = (HALF ? M1[a1 / 3] : M0[a1 / 3]);
      sx[m0 * 3 + a0 % 3] = (float)red[p].x;
      sx[m1 * 3 + a1 % 3] = (float)red[p].y;
    }
  }
}

__global__ __launch_bounds__(256, 4) void crossconv_kernel(
    const float* __restrict__ points,  // (2,1024,6)
    const float* __restrict__ W,       // (5,78,6)
    const float* __restrict__ bias,    // (5,6) flat 30
    float* __restrict__ out)           // (2,1024,33)
{
    __shared__ __align__(16) float sxyz[3 * NPTS];       // 12 KB coords f32
    __shared__ __align__(16) h2    sfeat[3 * NPTS / 2];  // 6 KB feats f16
    __shared__ __align__(16) float sx[2][80];

    const int tid    = threadIdx.x;
    const int lane   = tid & 63;
    const int w      = tid >> 6;          // wave in block: 0..3
    const int cLocal = w >> 1;            // center within block: 0,1
    const int half   = w & 1;             // probe half: 0,1
    const int G      = blockIdx.x * 2 + cLocal;   // global center 0..2047

    const float* batch = points + (G >> 10) * (NPTS * 6);

    // ---- one-time SoA transpose: thread t handles rows 4t..4t+3 ----
    {
      const float4* src4 = reinterpret_cast<const float4*>(batch) + 6 * tid;
      const float4 q0 = src4[0], q1 = src4[1], q2 = src4[2];
      const float4 q3 = src4[3], q4 = src4[4], q5 = src4[5];
      const int r = 4 * tid;
      // coords f32
      sxyz[0*NPTS + r+0] = q0.x; sxyz[1*NPTS + r+0] = q0.y; sxyz[2*NPTS + r+0] = q0.z;
      sxyz[0*NPTS + r+1] = q1.z; sxyz[1*NPTS + r+1] = q1.w; sxyz[2*NPTS + r+1] = q2.x;
      sxyz[0*NPTS + r+2] = q3.x; sxyz[1*NPTS + r+2] = q3.y; sxyz[2*NPTS + r+2] = q3.z;
      sxyz[0*NPTS + r+3] = q4.z; sxyz[1*NPTS + r+3] = q4.w; sxyz[2*NPTS + r+3] = q5.x;
      // features f16, packed by row pairs (rows r,r+1) and (r+2,r+3)
      const int h = r >> 1;  // h2 index of row pair
      sfeat[0*(NPTS/2) + h+0] = __builtin_amdgcn_cvt_pkrtz(q0.w, q2.y);  // f0 r,r+1
      sfeat[0*(NPTS/2) + h+1] = __builtin_amdgcn_cvt_pkrtz(q3.w, q5.y);  // f0 r+2,r+3
      sfeat[1*(NPTS/2) + h+0] = __builtin_amdgcn_cvt_pkrtz(q1.x, q2.z);  // f1 r,r+1
      sfeat[1*(NPTS/2) + h+1] = __builtin_amdgcn_cvt_pkrtz(q4.x, q5.z);  // f1 r+2,r+3
      sfeat[2*(NPTS/2) + h+0] = __builtin_amdgcn_cvt_pkrtz(q1.y, q2.w);  // f2 r,r+1
      sfeat[2*(NPTS/2) + h+1] = __builtin_amdgcn_cvt_pkrtz(q4.y, q5.w);  // f2 r+2,r+3
    }
    __syncthreads();

    const int   ci = ((blockIdx.x & 511) << 1) | cLocal;  // center row in batch
    const float cx = sxyz[0*NPTS + ci], cy = sxyz[1*NPTS + ci], cz = sxyz[2*NPTS + ci];
    const v2f cxp = {cx, cx}, cyp = {cy, cy}, czp = {cz, cz};

    float acc[42];
    #pragma unroll
    for (int j = 0; j < 42; ++j) acc[j] = 0.f;

    if (half == 0) run_main<0>(sxyz, sfeat, lane, cxp, cyp, czp, acc);
    else           run_main<1>(sxyz, sfeat, lane, cxp, cyp, czp, acc);

    if (half == 0) reduce_store<0>(acc, lane, sx[cLocal]);
    else           reduce_store<1>(acc, lane, sx[cLocal]);
    __syncthreads();

    // tail: waves with half==0 do the 78->30 matmul + coords for their center
    if (half == 0) {
      const float scale = COEFF / (float)NPTS;
      float* orow = out + G * 33;
      if (lane < 30) {
        const int k = lane / 6, o = lane % 6;
        const float* Wk = W + k * (78 * 6) + o;  // W[k, t, o], stride 6 over t
        float h0 = 0.f, h1 = 0.f, h2_ = 0.f, h3 = 0.f;
        const float4* sxv = reinterpret_cast<const float4*>(sx[cLocal]);
        #pragma unroll
        for (int t4 = 0; t4 < 19; ++t4) {
          const float4 v = sxv[t4];
          h0  = fmaf(v.x, Wk[(t4 * 4 + 0) * 6], h0);
          h1  = fmaf(v.y, Wk[(t4 * 4 + 1) * 6], h1);
          h2_ = fmaf(v.z, Wk[(t4 * 4 + 2) * 6], h2_);
          h3  = fmaf(v.w, Wk[(t4 * 4 + 3) * 6], h3);
        }
        const float2 vt = *reinterpret_cast<const float2*>(&sx[cLocal][76]);
        h0 = fmaf(vt.x, Wk[76 * 6], h0);
        h1 = fmaf(vt.y, Wk[77 * 6], h1);
        const float dot = (h0 + h2_) + (h1 + h3);
        float h = fmaf(dot, scale, bias[lane]);
        h = (h > 0.f) ? h : NEG * h;
        orow[3 + lane] = h;
      } else if (lane < 33) {
        orow[lane - 30] = (lane == 30) ? cx : ((lane == 31) ? cy : cz);
      }
    }
}

extern "C" void kernel_launch(void* const* d_in, const int* in_sizes, int n_in,
                              void* d_out, int out_size, void* d_ws, size_t ws_size,
                              hipStream_t stream) {
    const float* points = (const float*)d_in[0];  // 2*1024*6
    const float* W      = (const float*)d_in[1];  // 5*78*6
    const float* bias   = (const float*)d_in[2];  // 30
    float* out          = (float*)d_out;          // 2*1024*33
    // 1024 blocks x 4 waves = 2048 centers x 2 probe-halves
    crossconv_kernel<<<1024, 256, 0, stream>>>(points, W, bias, out);
}